// Round 3
// baseline (1185.930 us; speedup 1.0000x reference)
//
#include <hip/hip_runtime.h>

// Bidirectional LSTM, I=7, H=64, O=3, B=256, T=2048.
// Output = concat(h_fwd after T steps, h_bwd after ONE step on x[T-1]) @ W_lin^T + b_lin.
// One block per batch element (256 blocks ~ 1/CU), 256 threads = 4 waves.
//
// Round-3 change: replace v_readlane h-broadcast (SGPR hazard suspect) with
// DPP wave-rotation of an in-register h copy. Two counter-rotating chains
// (wave_ror:1 / wave_rol:1) cover all 64 k's; weights are pre-gathered in
// rotated per-lane order. Rotation direction is probed at runtime so the
// kernel is correct under either DPP direction convention.

#define TSEQ 2048
#define IN   7

__device__ __forceinline__ float fast_sigmoid(float x) {
    float e = __builtin_amdgcn_exp2f(-1.4426950408889634f * x);   // 2^(-x*log2e)
    return __builtin_amdgcn_rcpf(1.0f + e);
}
__device__ __forceinline__ float fast_tanh(float x) {
    x = fminf(12.0f, fmaxf(-12.0f, x));
    float e = __builtin_amdgcn_exp2f(2.8853900817779268f * x);    // 2^(2x*log2e)
    return (e - 1.0f) * __builtin_amdgcn_rcpf(e + 1.0f);
}

// full-wave rotate by 1 lane, both directions (VALU, no SGPR, no LDS)
__device__ __forceinline__ float wror1(float v) {
    return __uint_as_float(__builtin_amdgcn_mov_dpp(__float_as_uint(v), 0x13C, 0xF, 0xF, false));
}
__device__ __forceinline__ float wrol1(float v) {
    return __uint_as_float(__builtin_amdgcn_mov_dpp(__float_as_uint(v), 0x134, 0xF, 0xF, false));
}

__global__ __launch_bounds__(256, 1)
void bilstm_kernel(const float* __restrict__ x,      // [B, T, I]
                   const float* __restrict__ Wih_f,  // [256, 7]
                   const float* __restrict__ Whh_f,  // [256, 64]
                   const float* __restrict__ bih_f,  // [256]
                   const float* __restrict__ bhh_f,  // [256]
                   const float* __restrict__ Wih_b,  // [256, 7]
                   const float* __restrict__ bih_b,  // [256]
                   const float* __restrict__ bhh_b,  // [256]
                   const float* __restrict__ Wlin,   // [3, 128]
                   const float* __restrict__ blin,   // [3]
                   float* __restrict__ out)          // [B, 3]
{
    __shared__ __align__(16) float xs[TSEQ * IN];   // 57344 B: whole sequence, this batch elem
    __shared__ __align__(16) float zs[2][64][4];    // [buf][unit][class] gate activations
    __shared__ __align__(16) float hf[64];
    __shared__ __align__(16) float hbs[64];

    const int tid  = threadIdx.x;
    const int lane = tid & 63;
    const int cls  = tid >> 6;        // 0=i 1=f 2=g 3=o (wave-uniform)
    const int b    = blockIdx.x;

    // ---- stage x into LDS (coalesced) ----
    const float* xb = x + (size_t)b * (TSEQ * IN);
    for (int i = tid; i < TSEQ * IN; i += 256) xs[i] = xb[i];

    // ---- probe wave_ror direction: pl = (lane + d) & 63, d in {+1, -1 (=63)} ----
    int pl = __builtin_amdgcn_mov_dpp(lane, 0x13C, 0xF, 0xF, false);
    int dv = __builtin_amdgcn_readfirstlane(pl);   // lane 0's value: d & 63
    const int sd = (dv == 1) ? 1 : -1;

    // ---- per-thread weights in registers ----
    float wih[IN];
    #pragma unroll
    for (int i = 0; i < IN; ++i) wih[i] = Wih_f[tid * IN + i];
    const float bias = bih_f[tid] + bhh_f[tid];

    // rotated-order W_hh gathers: chain A (ror, offset +r*sd), chain B (rol, offset -r*sd)
    const float* wrow = Whh_f + tid * 64;
    float wA[32], wB33[33];
    #pragma unroll
    for (int r = 0; r < 32; ++r) wA[r] = wrow[(lane + r * sd) & 63];
    #pragma unroll
    for (int r = 1; r <= 32; ++r) wB33[r] = wrow[(lane - r * sd) & 63];

    float h = 0.0f;   // lane l holds h[l], replicated per wave
    float c = 0.0f;   // lane l holds c[l], replicated per wave
    __syncthreads();

    // ---- forward recurrence ----
    for (int t = 0; t < TSEQ; ++t) {
        const int p = t & 1;
        const float* xp = &xs[t * IN];

        float z0 = fmaf(xp[0], wih[0], fmaf(xp[1], wih[1], bias));
        float z1 = fmaf(xp[2], wih[2], xp[3] * wih[3]);
        float z2 = fmaf(xp[4], wih[4], xp[5] * wih[5]);
        float z3 = xp[6] * wih[6];

        // W_hh . h via two counter-rotating DPP chains (A: r=0..31, B: r=1..32)
        float hrA = h, hrB = h;
        #pragma unroll
        for (int r = 0; r < 32; ++r) {
            hrB = wrol1(hrB);                                   // -> offset -(r+1)*sd
            if (r & 1) z1 = fmaf(wA[r], hrA, z1);
            else       z0 = fmaf(wA[r], hrA, z0);               // offset +r*sd
            hrA = wror1(hrA);                                   // -> offset +(r+1)*sd
            if (r & 1) z3 = fmaf(wB33[r + 1], hrB, z3);
            else       z2 = fmaf(wB33[r + 1], hrB, z2);
        }

        const float zv = (z0 + z1) + (z2 + z3);
        const float a  = (cls == 2) ? fast_tanh(zv) : fast_sigmoid(zv);
        zs[p][lane][cls] = a;
        __syncthreads();   // the ONLY barrier per step (zs double-buffered)

        // redundant finish in every wave: one ds_read_b128 per lane
        const float4 za = *(const float4*)zs[p][lane];   // x=i y=f z=g w=o
        c = fmaf(za.y, c, za.x * za.z);
        h = za.w * fast_tanh(c);
    }

    if (tid < 64) hf[tid] = h;    // wave 0 publishes forward final h

    // ---- backward direction: ONE step on x[T-1] from zero state ----
    float wib[IN];
    #pragma unroll
    for (int i = 0; i < IN; ++i) wib[i] = Wih_b[tid * IN + i];
    const float biasb = bih_b[tid] + bhh_b[tid];
    const float* xl = &xs[(TSEQ - 1) * IN];
    float zb = biasb;
    #pragma unroll
    for (int i = 0; i < IN; ++i) zb = fmaf(xl[i], wib[i], zb);
    const float ab = (cls == 2) ? fast_tanh(zb) : fast_sigmoid(zb);
    __syncthreads();
    zs[0][lane][cls] = ab;
    __syncthreads();

    if (tid < 64) {
        const float4 za = *(const float4*)zs[0][tid];
        hbs[tid] = za.w * fast_tanh(za.x * za.z);   // c0=0 -> c = i*g
    }
    __syncthreads();

    // ---- final linear ----
    if (tid < 3) {
        const float* wl = Wlin + tid * 128;
        float s = blin[tid];
        #pragma unroll 8
        for (int j = 0; j < 64; ++j) s = fmaf(hf[j], wl[j], s);
        #pragma unroll 8
        for (int j = 0; j < 64; ++j) s = fmaf(hbs[j], wl[64 + j], s);
        out[b * 3 + tid] = s;
    }
}

extern "C" void kernel_launch(void* const* d_in, const int* in_sizes, int n_in,
                              void* d_out, int out_size, void* d_ws, size_t ws_size,
                              hipStream_t stream) {
    const float* x      = (const float*)d_in[0];
    const float* Wih_f  = (const float*)d_in[1];
    const float* Whh_f  = (const float*)d_in[2];
    const float* bih_f  = (const float*)d_in[3];
    const float* bhh_f  = (const float*)d_in[4];
    const float* Wih_b  = (const float*)d_in[5];
    // d_in[6] = W_hh_bwd: unused (backward runs exactly one step from h0=0)
    const float* bih_b  = (const float*)d_in[7];
    const float* bhh_b  = (const float*)d_in[8];
    const float* Wlin   = (const float*)d_in[9];
    const float* blin   = (const float*)d_in[10];
    float* out = (float*)d_out;

    bilstm_kernel<<<256, 256, 0, stream>>>(x, Wih_f, Whh_f, bih_f, bhh_f,
                                           Wih_b, bih_b, bhh_b, Wlin, blin, out);
}

// Round 5
// 957.131 us; speedup vs baseline: 1.2390x; 1.2390x over previous
//
#include <hip/hip_runtime.h>

// Bidirectional LSTM, I=7, H=64, O=3, B=256, T=2048.
// Output = concat(h_fwd after T steps, h_bwd after ONE step on x[T-1]) @ W_lin^T + b_lin.
//
// Round-5 = round-4 with the type fix: half2v must be __fp16-based to match
// __builtin_amdgcn_cvt_pkrtz's return type on gfx950.
//
// ONE WAVE PER BATCH ELEMENT — barrier-free recurrence.
// Lane l owns unit l: gate rows {l, 64+l, 128+l, 192+l}, so i,f,g,o for unit l
// are all produced in lane l; the c/h update is lane-local. No __syncthreads,
// no LDS round-trip in the recurrence. MAC work (256/lane/step) is halved with
// v_dot2_f32_f16 (f16 inputs, fp32 accumulate). h is packed to f16 pairs
// in-register (DPP neighbor swap + cvt_pkrtz) and broadcast via v_readlane ->
// SGPR operand of the dot2. x is staged to LDS as f16 [t][8] and read as one
// broadcast b128 per step, prefetched one step ahead.

typedef __fp16 half2v __attribute__((ext_vector_type(2)));

#define TSEQ 2048
#define IN   7

__device__ __forceinline__ float fast_sigmoid(float x) {
    float e = __builtin_amdgcn_exp2f(-1.4426950408889634f * x);   // 2^(-x*log2e)
    return __builtin_amdgcn_rcpf(1.0f + e);
}
__device__ __forceinline__ float fast_tanh(float x) {
    x = fminf(12.0f, fmaxf(-12.0f, x));
    float e = __builtin_amdgcn_exp2f(2.8853900817779268f * x);    // 2^(2x*log2e)
    return (e - 1.0f) * __builtin_amdgcn_rcpf(e + 1.0f);
}
__device__ __forceinline__ half2v h2i(int v)    { return __builtin_bit_cast(half2v, v); }
__device__ __forceinline__ int    i2h(half2v v) { return __builtin_bit_cast(int, v); }
__device__ __forceinline__ half2v pk(float a, float b) { return __builtin_amdgcn_cvt_pkrtz(a, b); }
__device__ __forceinline__ float  dot2(half2v a, half2v b, float c) {
    return __builtin_amdgcn_fdot2(a, b, c, false);
}

__global__ __launch_bounds__(64, 1)
void bilstm_kernel(const float* __restrict__ x,      // [B, T, I]
                   const float* __restrict__ Wih_f,  // [256, 7]
                   const float* __restrict__ Whh_f,  // [256, 64]
                   const float* __restrict__ bih_f,  // [256]
                   const float* __restrict__ bhh_f,  // [256]
                   const float* __restrict__ Wih_b,  // [256, 7]
                   const float* __restrict__ bih_b,  // [256]
                   const float* __restrict__ bhh_b,  // [256]
                   const float* __restrict__ Wlin,   // [3, 128]
                   const float* __restrict__ blin,   // [3]
                   float* __restrict__ out)          // [B, 3]
{
    // 40 KB LDS -> at most 4 blocks/CU -> never 2 waves on one SIMD
    __shared__ __align__(16) __fp16 xh[TSEQ * 8 + 4096];

    const int lane = threadIdx.x;      // 0..63, one wave
    const int b    = blockIdx.x;

    // ---- stage x as f16, layout [t][8] = {x0..x6, 0} (16 B, aligned) ----
    const float* xb = x + (size_t)b * (TSEQ * IN);
    for (int t = lane; t < TSEQ; t += 64) {
        const float* xp = xb + t * IN;
        int4 w;
        w.x = i2h(pk(xp[0], xp[1]));
        w.y = i2h(pk(xp[2], xp[3]));
        w.z = i2h(pk(xp[4], xp[5]));
        w.w = i2h(pk(xp[6], 0.0f));
        *(int4*)&xh[t * 8] = w;
    }

    // ---- pack forward weights: lane l owns rows l, 64+l, 128+l, 192+l ----
    float  bias[4];
    half2v wih[4][4];
    half2v whh[4][32];     // 128 VGPRs
    #pragma unroll
    for (int g = 0; g < 4; ++g) {
        const int r = g * 64 + lane;
        bias[g] = bih_f[r] + bhh_f[r];
        const float* wr = Wih_f + r * IN;
        wih[g][0] = pk(wr[0], wr[1]);
        wih[g][1] = pk(wr[2], wr[3]);
        wih[g][2] = pk(wr[4], wr[5]);
        wih[g][3] = pk(wr[6], 0.0f);
        const float* hr = Whh_f + r * 64;
        #pragma unroll
        for (int j = 0; j < 32; ++j) whh[g][j] = pk(hr[2*j], hr[2*j+1]);
    }

    float h = 0.0f, c = 0.0f;
    const bool ev = (lane & 1) == 0;

    int4 xcur = *(const int4*)&xh[0];   // x_0 (waits on staging via lgkmcnt)

    // ---- forward recurrence: barrier-free, LDS-free except x broadcast ----
    for (int t = 0; t < TSEQ; ++t) {
        // pack (h[2r], h[2r+1]) into lane pair 2r/2r+1 (identical value in both)
        float hn = __int_as_float(
            __builtin_amdgcn_mov_dpp(__float_as_int(h), 0xB1, 0xF, 0xF, false)); // swap 0<->1, 2<->3
        half2v hp = pk(ev ? h : hn, ev ? hn : h);

        const int4 xq = xcur;
        xcur = *(const int4*)&xh[((t + 1) & (TSEQ - 1)) * 8];   // prefetch next step

        float a0 = bias[0], a1 = bias[1], a2 = bias[2], a3 = bias[3];
        float b0 = 0.0f, b1 = 0.0f, b2 = 0.0f, b3 = 0.0f;

        // input projection (8 values incl. zero pad)
        {
            const half2v x0 = h2i(xq.x), x1 = h2i(xq.y), x2 = h2i(xq.z), x3 = h2i(xq.w);
            a0 = dot2(x0, wih[0][0], a0);  a1 = dot2(x0, wih[1][0], a1);
            a2 = dot2(x0, wih[2][0], a2);  a3 = dot2(x0, wih[3][0], a3);
            b0 = dot2(x1, wih[0][1], b0);  b1 = dot2(x1, wih[1][1], b1);
            b2 = dot2(x1, wih[2][1], b2);  b3 = dot2(x1, wih[3][1], b3);
            a0 = dot2(x2, wih[0][2], a0);  a1 = dot2(x2, wih[1][2], a1);
            a2 = dot2(x2, wih[2][2], a2);  a3 = dot2(x2, wih[3][2], a3);
            b0 = dot2(x3, wih[0][3], b0);  b1 = dot2(x3, wih[1][3], b1);
            b2 = dot2(x3, wih[2][3], b2);  b3 = dot2(x3, wih[3][3], b3);
        }

        // W_hh . h : 32 pair-broadcasts (readlane -> SGPR), 4 dot2 each
        #pragma unroll
        for (int r = 0; r < 32; ++r) {
            const half2v pb = h2i(__builtin_amdgcn_readlane(i2h(hp), 2 * r));
            if (r & 1) {
                b0 = dot2(pb, whh[0][r], b0);
                b1 = dot2(pb, whh[1][r], b1);
                b2 = dot2(pb, whh[2][r], b2);
                b3 = dot2(pb, whh[3][r], b3);
            } else {
                a0 = dot2(pb, whh[0][r], a0);
                a1 = dot2(pb, whh[1][r], a1);
                a2 = dot2(pb, whh[2][r], a2);
                a3 = dot2(pb, whh[3][r], a3);
            }
        }

        const float zi = a0 + b0, zf = a1 + b1, zg = a2 + b2, zo = a3 + b3;
        const float ai = fast_sigmoid(zi);
        const float af = fast_sigmoid(zf);
        const float ag = fast_tanh(zg);
        const float ao = fast_sigmoid(zo);
        c = fmaf(af, c, ai * ag);
        h = ao * fast_tanh(c);     // lane l holds h[l]; feeds next step's pack
    }

    // ---- backward direction: ONE step on x[T-1] from zero state ----
    float hbv;
    {
        const int4 xq = *(const int4*)&xh[(TSEQ - 1) * 8];
        const half2v x0 = h2i(xq.x), x1 = h2i(xq.y), x2 = h2i(xq.z), x3 = h2i(xq.w);
        float zb[4];
        #pragma unroll
        for (int g = 0; g < 4; ++g) {
            const int r = g * 64 + lane;
            const float* wr = Wih_b + r * IN;
            float z = bih_b[r] + bhh_b[r];
            z = dot2(x0, pk(wr[0], wr[1]), z);
            z = dot2(x1, pk(wr[2], wr[3]), z);
            z = dot2(x2, pk(wr[4], wr[5]), z);
            z = dot2(x3, pk(wr[6], 0.0f), z);
            zb[g] = z;
        }
        const float ai = fast_sigmoid(zb[0]);
        const float ag = fast_tanh(zb[2]);
        const float ao = fast_sigmoid(zb[3]);
        hbv = ao * fast_tanh(ai * ag);    // c0 = 0 -> c = i*g
    }

    // ---- final linear via per-lane partials + wave reduction ----
    // out[b][o] = blin[o] + sum_j hf[j]*Wlin[o][j] + hb[j]*Wlin[o][64+j]
    float s0 = fmaf(h, Wlin[0 * 128 + lane], hbv * Wlin[0 * 128 + 64 + lane]);
    float s1 = fmaf(h, Wlin[1 * 128 + lane], hbv * Wlin[1 * 128 + 64 + lane]);
    float s2 = fmaf(h, Wlin[2 * 128 + lane], hbv * Wlin[2 * 128 + 64 + lane]);
    #pragma unroll
    for (int off = 32; off > 0; off >>= 1) {
        s0 += __shfl_xor(s0, off, 64);
        s1 += __shfl_xor(s1, off, 64);
        s2 += __shfl_xor(s2, off, 64);
    }
    if (lane == 0) {
        out[b * 3 + 0] = s0 + blin[0];
        out[b * 3 + 1] = s1 + blin[1];
        out[b * 3 + 2] = s2 + blin[2];
    }
}

extern "C" void kernel_launch(void* const* d_in, const int* in_sizes, int n_in,
                              void* d_out, int out_size, void* d_ws, size_t ws_size,
                              hipStream_t stream) {
    const float* x      = (const float*)d_in[0];
    const float* Wih_f  = (const float*)d_in[1];
    const float* Whh_f  = (const float*)d_in[2];
    const float* bih_f  = (const float*)d_in[3];
    const float* bhh_f  = (const float*)d_in[4];
    const float* Wih_b  = (const float*)d_in[5];
    // d_in[6] = W_hh_bwd: unused (backward runs exactly one step from h0=0)
    const float* bih_b  = (const float*)d_in[7];
    const float* bhh_b  = (const float*)d_in[8];
    const float* Wlin   = (const float*)d_in[9];
    const float* blin   = (const float*)d_in[10];
    float* out = (float*)d_out;

    bilstm_kernel<<<256, 64, 0, stream>>>(x, Wih_f, Whh_f, bih_f, bhh_f,
                                          Wih_b, bih_b, bhh_b, Wlin, blin, out);
}

// Round 6
// 945.878 us; speedup vs baseline: 1.2538x; 1.0119x over previous
//
#include <hip/hip_runtime.h>

// Bidirectional LSTM, I=7, H=64, O=3, B=256, T=2048.
// Output = concat(h_fwd after T steps, h_bwd after ONE step on x[T-1]) @ W_lin^T + b_lin.
//
// Round-6: round-5 structure (one wave per batch element, barrier-free,
// v_dot2_f32_f16) with:
//  1. amdgpu_waves_per_eu(1,1): pin 1 wave/EU so the allocator uses the full
//     ~512-reg budget and whh (128 VGPRs) stays in real VGPRs (round-5's
//     VGPR_Count=132 meant whh was parked in AGPR/scratch -> per-step restore
//     bloat, ~944 busy cyc/step vs ~434 expected).
//  2. bias folded into the x padding slot (pad=1.0, wih[g][3]=(w6,bias_g)).
//  3. h-pack cndmasks dropped (readlane only reads even lanes).
//  4. clamp-free tanh(x) = 2*sigmoid(2x)-1 (exp2 saturates cleanly).

typedef __fp16 half2v __attribute__((ext_vector_type(2)));

#define TSEQ 2048
#define IN   7

__device__ __forceinline__ float fast_sigmoid(float x) {
    float e = __builtin_amdgcn_exp2f(-1.4426950408889634f * x);   // 2^(-x*log2e)
    return __builtin_amdgcn_rcpf(1.0f + e);
}
// tanh(x) = 2/(1+exp2(-2x*log2e)) - 1 ; exp2 saturates to 0/inf -> +-1, no clamp
__device__ __forceinline__ float fast_tanh(float x) {
    float e = __builtin_amdgcn_exp2f(-2.8853900817779268f * x);
    return fmaf(2.0f, __builtin_amdgcn_rcpf(1.0f + e), -1.0f);
}
__device__ __forceinline__ half2v h2i(int v)    { return __builtin_bit_cast(half2v, v); }
__device__ __forceinline__ int    i2h(half2v v) { return __builtin_bit_cast(int, v); }
__device__ __forceinline__ half2v pk(float a, float b) { return __builtin_amdgcn_cvt_pkrtz(a, b); }
__device__ __forceinline__ float  dot2(half2v a, half2v b, float c) {
    return __builtin_amdgcn_fdot2(a, b, c, false);
}

__global__ __launch_bounds__(64)
__attribute__((amdgpu_waves_per_eu(1, 1)))
void bilstm_kernel(const float* __restrict__ x,      // [B, T, I]
                   const float* __restrict__ Wih_f,  // [256, 7]
                   const float* __restrict__ Whh_f,  // [256, 64]
                   const float* __restrict__ bih_f,  // [256]
                   const float* __restrict__ bhh_f,  // [256]
                   const float* __restrict__ Wih_b,  // [256, 7]
                   const float* __restrict__ bih_b,  // [256]
                   const float* __restrict__ bhh_b,  // [256]
                   const float* __restrict__ Wlin,   // [3, 128]
                   const float* __restrict__ blin,   // [3]
                   float* __restrict__ out)          // [B, 3]
{
    // 40 KB LDS; occupancy pinned to 1 wave/EU anyway
    __shared__ __align__(16) __fp16 xh[TSEQ * 8 + 4096];

    const int lane = threadIdx.x;      // 0..63, one wave
    const int b    = blockIdx.x;

    // ---- stage x as f16, layout [t][8] = {x0..x6, 1.0} (pad carries bias) ----
    const float* xb = x + (size_t)b * (TSEQ * IN);
    for (int t = lane; t < TSEQ; t += 64) {
        const float* xp = xb + t * IN;
        int4 w;
        w.x = i2h(pk(xp[0], xp[1]));
        w.y = i2h(pk(xp[2], xp[3]));
        w.z = i2h(pk(xp[4], xp[5]));
        w.w = i2h(pk(xp[6], 1.0f));    // pad = 1.0 -> dot2 with (w6, bias)
        *(int4*)&xh[t * 8] = w;
    }

    // ---- pack forward weights: lane l owns rows l, 64+l, 128+l, 192+l ----
    half2v wih[4][4];
    half2v whh[4][32];     // 128 VGPRs — must stay in VGPRs (waves_per_eu(1,1))
    #pragma unroll
    for (int g = 0; g < 4; ++g) {
        const int r = g * 64 + lane;
        const float biasg = bih_f[r] + bhh_f[r];
        const float* wr = Wih_f + r * IN;
        wih[g][0] = pk(wr[0], wr[1]);
        wih[g][1] = pk(wr[2], wr[3]);
        wih[g][2] = pk(wr[4], wr[5]);
        wih[g][3] = pk(wr[6], biasg);          // bias rides the 1.0 pad
        const float* hr = Whh_f + r * 64;
        #pragma unroll
        for (int j = 0; j < 32; ++j) whh[g][j] = pk(hr[2*j], hr[2*j+1]);
    }

    float h = 0.0f, c = 0.0f;

    int4 xcur = *(const int4*)&xh[0];   // x_0 (waits on staging via lgkmcnt)

    // ---- forward recurrence: barrier-free, LDS-free except x broadcast ----
    for (int t = 0; t < TSEQ; ++t) {
        // even lane 2r: hp = (h[2r], h[2r+1]); odd lanes hold garbage order,
        // but readlane below only reads even lanes.
        float hn = __int_as_float(
            __builtin_amdgcn_mov_dpp(__float_as_int(h), 0xB1, 0xF, 0xF, false)); // swap 0<->1
        half2v hp = pk(h, hn);

        const int4 xq = xcur;
        xcur = *(const int4*)&xh[((t + 1) & (TSEQ - 1)) * 8];   // prefetch next step

        float a0 = 0.0f, a1 = 0.0f, a2 = 0.0f, a3 = 0.0f;
        float b0 = 0.0f, b1 = 0.0f, b2 = 0.0f, b3 = 0.0f;

        // input projection + bias (8 values incl. 1.0 pad)
        {
            const half2v x0 = h2i(xq.x), x1 = h2i(xq.y), x2 = h2i(xq.z), x3 = h2i(xq.w);
            a0 = dot2(x0, wih[0][0], a0);  a1 = dot2(x0, wih[1][0], a1);
            a2 = dot2(x0, wih[2][0], a2);  a3 = dot2(x0, wih[3][0], a3);
            b0 = dot2(x1, wih[0][1], b0);  b1 = dot2(x1, wih[1][1], b1);
            b2 = dot2(x1, wih[2][1], b2);  b3 = dot2(x1, wih[3][1], b3);
            a0 = dot2(x2, wih[0][2], a0);  a1 = dot2(x2, wih[1][2], a1);
            a2 = dot2(x2, wih[2][2], a2);  a3 = dot2(x2, wih[3][2], a3);
            b0 = dot2(x3, wih[0][3], b0);  b1 = dot2(x3, wih[1][3], b1);
            b2 = dot2(x3, wih[2][3], b2);  b3 = dot2(x3, wih[3][3], b3);
        }

        // W_hh . h : 32 pair-broadcasts (readlane of even lanes), 4 dot2 each
        #pragma unroll
        for (int r = 0; r < 32; ++r) {
            const half2v pb = h2i(__builtin_amdgcn_readlane(i2h(hp), 2 * r));
            if (r & 1) {
                b0 = dot2(pb, whh[0][r], b0);
                b1 = dot2(pb, whh[1][r], b1);
                b2 = dot2(pb, whh[2][r], b2);
                b3 = dot2(pb, whh[3][r], b3);
            } else {
                a0 = dot2(pb, whh[0][r], a0);
                a1 = dot2(pb, whh[1][r], a1);
                a2 = dot2(pb, whh[2][r], a2);
                a3 = dot2(pb, whh[3][r], a3);
            }
        }

        const float zi = a0 + b0, zf = a1 + b1, zg = a2 + b2, zo = a3 + b3;
        const float ai = fast_sigmoid(zi);
        const float af = fast_sigmoid(zf);
        const float ag = fast_tanh(zg);
        const float ao = fast_sigmoid(zo);
        c = fmaf(af, c, ai * ag);
        h = ao * fast_tanh(c);     // lane l holds h[l]; feeds next step's pack
    }

    // ---- backward direction: ONE step on x[T-1] from zero state ----
    float hbv;
    {
        const int4 xq = *(const int4*)&xh[(TSEQ - 1) * 8];
        const half2v x0 = h2i(xq.x), x1 = h2i(xq.y), x2 = h2i(xq.z), x3 = h2i(xq.w);
        float zb[4];
        #pragma unroll
        for (int g = 0; g < 4; ++g) {
            const int r = g * 64 + lane;
            const float* wr = Wih_b + r * IN;
            float z = bih_b[r] + bhh_b[r];
            z = dot2(x0, pk(wr[0], wr[1]), z);
            z = dot2(x1, pk(wr[2], wr[3]), z);
            z = dot2(x2, pk(wr[4], wr[5]), z);
            z = dot2(x3, pk(wr[6], 0.0f), z);   // pad=1.0 times 0 weight = 0
            zb[g] = z;
        }
        const float ai = fast_sigmoid(zb[0]);
        const float ag = fast_tanh(zb[2]);
        const float ao = fast_sigmoid(zb[3]);
        hbv = ao * fast_tanh(ai * ag);    // c0 = 0 -> c = i*g
    }

    // ---- final linear via per-lane partials + wave reduction ----
    float s0 = fmaf(h, Wlin[0 * 128 + lane], hbv * Wlin[0 * 128 + 64 + lane]);
    float s1 = fmaf(h, Wlin[1 * 128 + lane], hbv * Wlin[1 * 128 + 64 + lane]);
    float s2 = fmaf(h, Wlin[2 * 128 + lane], hbv * Wlin[2 * 128 + 64 + lane]);
    #pragma unroll
    for (int off = 32; off > 0; off >>= 1) {
        s0 += __shfl_xor(s0, off, 64);
        s1 += __shfl_xor(s1, off, 64);
        s2 += __shfl_xor(s2, off, 64);
    }
    if (lane == 0) {
        out[b * 3 + 0] = s0 + blin[0];
        out[b * 3 + 1] = s1 + blin[1];
        out[b * 3 + 2] = s2 + blin[2];
    }
}

extern "C" void kernel_launch(void* const* d_in, const int* in_sizes, int n_in,
                              void* d_out, int out_size, void* d_ws, size_t ws_size,
                              hipStream_t stream) {
    const float* x      = (const float*)d_in[0];
    const float* Wih_f  = (const float*)d_in[1];
    const float* Whh_f  = (const float*)d_in[2];
    const float* bih_f  = (const float*)d_in[3];
    const float* bhh_f  = (const float*)d_in[4];
    const float* Wih_b  = (const float*)d_in[5];
    // d_in[6] = W_hh_bwd: unused (backward runs exactly one step from h0=0)
    const float* bih_b  = (const float*)d_in[7];
    const float* bhh_b  = (const float*)d_in[8];
    const float* Wlin   = (const float*)d_in[9];
    const float* blin   = (const float*)d_in[10];
    float* out = (float*)d_out;

    bilstm_kernel<<<256, 64, 0, stream>>>(x, Wih_f, Whh_f, bih_f, bhh_f,
                                          Wih_b, bih_b, bhh_b, Wlin, blin, out);
}

// Round 7
// 923.413 us; speedup vs baseline: 1.2843x; 1.0243x over previous
//
#include <hip/hip_runtime.h>

// Bidirectional LSTM, I=7, H=64, O=3, B=256, T=2048.
// Output = concat(h_fwd after T steps, h_bwd after ONE step on x[T-1]) @ W_lin^T + b_lin.
//
// Round-7: one wave per batch element, barrier-free (round-5 structure), with
// the readlane/SGPR broadcast replaced by a pure-VGPR scheme:
//   - per step, gather h into packed f16 pairs ONCE via 2x ds_bpermute:
//     lane l holds pair (h[2m], h[2m+1]), m = l&31 (duplicated across halves;
//     (x mod 64) mod 32 == x mod 32 makes rotation indices consistent).
//   - cycle the 32 pairs through every lane with a v_mov_dpp wave_ror:1 chain
//     (direction probed at runtime; weights pre-gathered in rotated order).
// Inner loop: 2 bperm + pk + 32*(dpp + 4 dot2) + 16 input dot2 + activations.
// No SGPR writes, no readlane, 4 accumulators.

typedef __fp16 half2v __attribute__((ext_vector_type(2)));

#define TSEQ 2048
#define IN   7

__device__ __forceinline__ float fast_sigmoid(float x) {
    float e = __builtin_amdgcn_exp2f(-1.4426950408889634f * x);   // 2^(-x*log2e)
    return __builtin_amdgcn_rcpf(1.0f + e);
}
// tanh(x) = 2/(1+exp2(-2x*log2e)) - 1 ; exp2 saturates to 0/inf -> +-1, no clamp
__device__ __forceinline__ float fast_tanh(float x) {
    float e = __builtin_amdgcn_exp2f(-2.8853900817779268f * x);
    return fmaf(2.0f, __builtin_amdgcn_rcpf(1.0f + e), -1.0f);
}
__device__ __forceinline__ half2v h2i(int v)    { return __builtin_bit_cast(half2v, v); }
__device__ __forceinline__ int    i2h(half2v v) { return __builtin_bit_cast(int, v); }
__device__ __forceinline__ half2v pk(float a, float b) { return __builtin_amdgcn_cvt_pkrtz(a, b); }
__device__ __forceinline__ float  dot2(half2v a, half2v b, float c) {
    return __builtin_amdgcn_fdot2(a, b, c, false);
}
// full-wave rotate by 1 lane (VALU DPP, no SGPR, no LDS)
__device__ __forceinline__ int wror1_i(int v) {
    return __builtin_amdgcn_mov_dpp(v, 0x13C, 0xF, 0xF, false);
}

__global__ __launch_bounds__(64)
__attribute__((amdgpu_waves_per_eu(1, 1)))
void bilstm_kernel(const float* __restrict__ x,      // [B, T, I]
                   const float* __restrict__ Wih_f,  // [256, 7]
                   const float* __restrict__ Whh_f,  // [256, 64]
                   const float* __restrict__ bih_f,  // [256]
                   const float* __restrict__ bhh_f,  // [256]
                   const float* __restrict__ Wih_b,  // [256, 7]
                   const float* __restrict__ bih_b,  // [256]
                   const float* __restrict__ bhh_b,  // [256]
                   const float* __restrict__ Wlin,   // [3, 128]
                   const float* __restrict__ blin,   // [3]
                   float* __restrict__ out)          // [B, 3]
{
    __shared__ __align__(16) __fp16 xh[TSEQ * 8 + 64];   // ~33 KB

    const int lane = threadIdx.x;      // 0..63, one wave
    const int b    = blockIdx.x;

    // ---- stage x as f16, layout [t][8] = {x0..x6, 1.0} (pad carries bias) ----
    const float* xb = x + (size_t)b * (TSEQ * IN);
    for (int t = lane; t < TSEQ; t += 64) {
        const float* xp = xb + t * IN;
        int4 w;
        w.x = i2h(pk(xp[0], xp[1]));
        w.y = i2h(pk(xp[2], xp[3]));
        w.z = i2h(pk(xp[4], xp[5]));
        w.w = i2h(pk(xp[6], 1.0f));    // pad = 1.0 -> dot2 with (w6, bias)
        *(int4*)&xh[t * 8] = w;
    }

    // ---- probe wave_ror direction: after 1 ror, lane l holds old lane (l+dv)&63 ----
    const int dv = __builtin_amdgcn_readfirstlane(wror1_i(lane));   // 1 or 63

    // ---- pack forward weights: lane l owns rows l, 64+l, 128+l, 192+l ----
    // whh[g][r] pairs pre-gathered in ROTATED order: at iteration r the hp
    // register in lane l holds pair ((l + r*dv) & 31).
    half2v wih[4][4];
    half2v whh[4][32];     // 128 VGPRs
    #pragma unroll
    for (int g = 0; g < 4; ++g) {
        const int r0 = g * 64 + lane;
        const float biasg = bih_f[r0] + bhh_f[r0];
        const float* wr = Wih_f + r0 * IN;
        wih[g][0] = pk(wr[0], wr[1]);
        wih[g][1] = pk(wr[2], wr[3]);
        wih[g][2] = pk(wr[4], wr[5]);
        wih[g][3] = pk(wr[6], biasg);          // bias rides the 1.0 pad
        const float* hr = Whh_f + r0 * 64;
        for (int r = 0; r < 32; ++r) {
            const int p = (lane + r * dv) & 31;
            whh[g][r] = pk(hr[2 * p], hr[2 * p + 1]);
        }
    }

    // bpermute byte-addresses for the pair gather (precomputed, loop-invariant)
    const int adrE = ((lane & 31) * 2) * 4;        // lane of h[2m]
    const int adrO = ((lane & 31) * 2 + 1) * 4;    // lane of h[2m+1]

    float h = 0.0f, c = 0.0f;

    int4 xcur = *(const int4*)&xh[0];   // x_0 (waits on staging via lgkmcnt)

    // ---- forward recurrence: barrier-free ----
    for (int t = 0; t < TSEQ; ++t) {
        // gather h into packed pairs: lane l <- (h[2m], h[2m+1]), m = l&31
        const int hi = __float_as_int(h);
        const float hE = __int_as_float(__builtin_amdgcn_ds_bpermute(adrE, hi));
        const float hO = __int_as_float(__builtin_amdgcn_ds_bpermute(adrO, hi));
        int hp = i2h(pk(hE, hO));

        const int4 xq = xcur;
        xcur = *(const int4*)&xh[((t + 1) & (TSEQ - 1)) * 8];   // prefetch next step

        // input projection + bias (8 values incl. 1.0 pad) — independent of bperm,
        // covers the bpermute latency
        float z0, z1, z2, z3;
        {
            const half2v x0 = h2i(xq.x), x1 = h2i(xq.y), x2 = h2i(xq.z), x3 = h2i(xq.w);
            z0 = dot2(x0, wih[0][0], 0.0f);  z1 = dot2(x0, wih[1][0], 0.0f);
            z2 = dot2(x0, wih[2][0], 0.0f);  z3 = dot2(x0, wih[3][0], 0.0f);
            z0 = dot2(x1, wih[0][1], z0);    z1 = dot2(x1, wih[1][1], z1);
            z2 = dot2(x1, wih[2][1], z2);    z3 = dot2(x1, wih[3][1], z3);
            z0 = dot2(x2, wih[0][2], z0);    z1 = dot2(x2, wih[1][2], z1);
            z2 = dot2(x2, wih[2][2], z2);    z3 = dot2(x2, wih[3][2], z3);
            z0 = dot2(x3, wih[0][3], z0);    z1 = dot2(x3, wih[1][3], z1);
            z2 = dot2(x3, wih[2][3], z2);    z3 = dot2(x3, wih[3][3], z3);
        }

        // W_hh . h : 32 rotations of the packed-pair register, 4 dot2 each
        #pragma unroll
        for (int r = 0; r < 32; ++r) {
            const half2v pb = h2i(hp);
            z0 = dot2(pb, whh[0][r], z0);
            z1 = dot2(pb, whh[1][r], z1);
            z2 = dot2(pb, whh[2][r], z2);
            z3 = dot2(pb, whh[3][r], z3);
            if (r < 31) hp = wror1_i(hp);
        }

        const float ai = fast_sigmoid(z0);
        const float af = fast_sigmoid(z1);
        const float ag = fast_tanh(z2);
        const float ao = fast_sigmoid(z3);
        c = fmaf(af, c, ai * ag);
        h = ao * fast_tanh(c);     // lane l holds h[l]; feeds next step's gather
    }

    // ---- backward direction: ONE step on x[T-1] from zero state ----
    float hbv;
    {
        const int4 xq = *(const int4*)&xh[(TSEQ - 1) * 8];
        const half2v x0 = h2i(xq.x), x1 = h2i(xq.y), x2 = h2i(xq.z), x3 = h2i(xq.w);
        float zb[4];
        #pragma unroll
        for (int g = 0; g < 4; ++g) {
            const int r0 = g * 64 + lane;
            const float* wr = Wih_b + r0 * IN;
            float z = bih_b[r0] + bhh_b[r0];
            z = dot2(x0, pk(wr[0], wr[1]), z);
            z = dot2(x1, pk(wr[2], wr[3]), z);
            z = dot2(x2, pk(wr[4], wr[5]), z);
            z = dot2(x3, pk(wr[6], 0.0f), z);   // pad=1.0 times 0 weight = 0
            zb[g] = z;
        }
        const float ai = fast_sigmoid(zb[0]);
        const float ag = fast_tanh(zb[2]);
        const float ao = fast_sigmoid(zb[3]);
        hbv = ao * fast_tanh(ai * ag);    // c0 = 0 -> c = i*g
    }

    // ---- final linear via per-lane partials + wave reduction ----
    float s0 = fmaf(h, Wlin[0 * 128 + lane], hbv * Wlin[0 * 128 + 64 + lane]);
    float s1 = fmaf(h, Wlin[1 * 128 + lane], hbv * Wlin[1 * 128 + 64 + lane]);
    float s2 = fmaf(h, Wlin[2 * 128 + lane], hbv * Wlin[2 * 128 + 64 + lane]);
    #pragma unroll
    for (int off = 32; off > 0; off >>= 1) {
        s0 += __shfl_xor(s0, off, 64);
        s1 += __shfl_xor(s1, off, 64);
        s2 += __shfl_xor(s2, off, 64);
    }
    if (lane == 0) {
        out[b * 3 + 0] = s0 + blin[0];
        out[b * 3 + 1] = s1 + blin[1];
        out[b * 3 + 2] = s2 + blin[2];
    }
}

extern "C" void kernel_launch(void* const* d_in, const int* in_sizes, int n_in,
                              void* d_out, int out_size, void* d_ws, size_t ws_size,
                              hipStream_t stream) {
    const float* x      = (const float*)d_in[0];
    const float* Wih_f  = (const float*)d_in[1];
    const float* Whh_f  = (const float*)d_in[2];
    const float* bih_f  = (const float*)d_in[3];
    const float* bhh_f  = (const float*)d_in[4];
    const float* Wih_b  = (const float*)d_in[5];
    // d_in[6] = W_hh_bwd: unused (backward runs exactly one step from h0=0)
    const float* bih_b  = (const float*)d_in[7];
    const float* bhh_b  = (const float*)d_in[8];
    const float* Wlin   = (const float*)d_in[9];
    const float* blin   = (const float*)d_in[10];
    float* out = (float*)d_out;

    bilstm_kernel<<<256, 64, 0, stream>>>(x, Wih_f, Whh_f, bih_f, bhh_f,
                                          Wih_b, bih_b, bhh_b, Wlin, blin, out);
}